// Round 14
// baseline (325.191 us; speedup 1.0000x reference)
//
#include <hip/hip_runtime.h>
#include <stdint.h>

typedef unsigned short u16;
typedef __attribute__((ext_vector_type(8))) short short8;
typedef __attribute__((ext_vector_type(4))) float f32x4;

#define M_DIM 8192
#define N_DIM 4096
#define K_DIM 4096

// ---------- fp32 -> bf16 (RNE), 8 elems/thread ----------
__device__ inline u16 f32_to_bf16_rne(float f) {
    uint32_t b = __builtin_bit_cast(uint32_t, f);
    b += 0x7fffu + ((b >> 16) & 1u);
    return (u16)(b >> 16);
}

__global__ __launch_bounds__(256)
void cvt_f32_to_bf16_k(const float* __restrict__ in, u16* __restrict__ out, int n_vec8) {
    int stride = gridDim.x * blockDim.x;
    for (int i = blockIdx.x * blockDim.x + threadIdx.x; i < n_vec8; i += stride) {
        const float4* p = reinterpret_cast<const float4*>(in) + 2 * (size_t)i;
        float4 a = p[0];
        float4 b = p[1];
        float v[8] = {a.x, a.y, a.z, a.w, b.x, b.y, b.z, b.w};
        short8 r;
#pragma unroll
        for (int j = 0; j < 8; ++j) r[j] = (short)f32_to_bf16_rne(v[j]);
        *reinterpret_cast<short8*>(out + 8 * (size_t)i) = r;
    }
}

// ---------- 256x128 bf16 GEMM, BK=32, 2 blocks/CU (unsync TLP) ----------
// A: [M][K] bf16, B: [N][K] bf16 (B^T), C: [M][N] f32
// 256 threads = 4 waves (2M x 2N); per-wave output 128x64; BK=32.
// LDS per block: [2 dbuf][A 256x32 + B 128x32] bf16 = 48 KiB -> 2 blocks/CU.
// The two co-resident blocks are NOT barrier-synchronized: when one stalls at
// VM/BAR/LGKM, the other's waves feed the MFMA/LDS pipes (TLP overlap).
//
// Rows are 64 B (BK=32). Swizzle S(a) = a ^ (((a>>7)&3)<<4): XOR 16B-chunk
// index (bits 4-5) with (row>>1)&3 (bits 7-8). Involution; read pattern is
// conflict-free per 8-lane group, 2-way per 16 (free, m136). Chunk map for
// linear DMA dest: physical cp holds logical cl = (cp&~3)|((cp&3)^((cp>>3)&3)).
//
// Body t (tile t in buf[t&1]):
//   VM(6)   -> outstanding = t+1's 6 + t+2-not-yet; drains tile t's DMA
//   BAR     -> publish tile t
//   12 ds_read (8 A-frags + 4 B-frags); LGKM(0)+SB0; 32 MFMA (8m x 4n)
//   BAR     -> all waves done reading buf[t&1]
//   STAGE(tile t+2 -> buf[t&1])  (6 DMA; WAR-safe after the barrier)
// Prologue stages tiles 0,1 (12 DMA). vm ledger: at body-t VM(6), outstanding
// = tile t's 6 (oldest, if undrained) + t+1's 6 -> keeps newest 6 = t+1 OK.

#define BAR() do { asm volatile("" ::: "memory"); __builtin_amdgcn_s_barrier(); asm volatile("" ::: "memory"); } while (0)
#define LGKM0() do { asm volatile("s_waitcnt lgkmcnt(0)" ::: "memory"); __builtin_amdgcn_sched_barrier(0); } while (0)
#define WAIT_VM6() asm volatile("s_waitcnt vmcnt(6)" ::: "memory")
#define WAIT_VM0() asm volatile("s_waitcnt vmcnt(0)" ::: "memory")

#define MFMA32(AA, BB)                                                            \
    _Pragma("unroll")                                                             \
    for (int m = 0; m < 8; ++m) {                                                 \
        _Pragma("unroll")                                                         \
        for (int n = 0; n < 4; ++n) {                                             \
            acc[m][n] = __builtin_amdgcn_mfma_f32_16x16x32_bf16(                  \
                AA[m], BB[n], acc[m][n], 0, 0, 0);                                \
        }                                                                         \
    }

#define READ_A8(AA, P)                                                            \
    _Pragma("unroll")                                                             \
    for (int m = 0; m < 8; ++m) {                                                 \
        AA[m] = *reinterpret_cast<const short8*>((P) + m * 1024);                 \
    }

#define READ_B4(BB, P)                                                            \
    _Pragma("unroll")                                                             \
    for (int n = 0; n < 4; ++n) {                                                 \
        BB[n] = *reinterpret_cast<const short8*>((P) + n * 1024);                 \
    }

__global__ __launch_bounds__(256, 2)
void gemm_tlp(const u16* __restrict__ A, const u16* __restrict__ B,
              const float* __restrict__ bias, float* __restrict__ C) {
    // per buffer: A 256x32 (8192 u16) then B 128x32 (4096 u16) = 24 KiB
    __shared__ __align__(16) u16 lds[2][8192 + 4096];   // 48 KiB

    const int tid  = threadIdx.x;
    const int wave = tid >> 6;      // 0..3
    const int lane = tid & 63;

    // T1: XCD-aware bijective swizzle (nwg=1024, %8==0)
    const uint32_t nbx = N_DIM / 128;   // 32
    const uint32_t wg = (blockIdx.x & 7u) * 128u + (blockIdx.x >> 3);
    const int bx = (int)(wg % nbx);
    const int by = (int)(wg / nbx);
    const int brow = by * 256;
    const int bcol = bx * 128;

    const int wr = wave >> 1;   // 0..1 -> 128 output rows
    const int wc = wave & 1;    // 0..1 -> 64 output cols

    // DMA source chunk maps (16B chunks): A 1024 chunks (4/thread), B 512 (2/thread)
    uint32_t rA[4], cA[4], rB[2], cB[2];
#pragma unroll
    for (int j = 0; j < 4; ++j) {
        const uint32_t cp = (uint32_t)tid + 256u * j;
        const uint32_t cl = (cp & ~3u) | ((cp & 3u) ^ ((cp >> 3) & 3u));
        rA[j] = cl >> 2;  cA[j] = (cl & 3u) * 8u;
    }
#pragma unroll
    for (int j = 0; j < 2; ++j) {
        const uint32_t cp = (uint32_t)tid + 256u * j;
        const uint32_t cl = (cp & ~3u) | ((cp & 3u) ^ ((cp >> 3) & 3u));
        rB[j] = cl >> 2;  cB[j] = (cl & 3u) * 8u;
    }

    const u16* gA = A + (size_t)brow * K_DIM;
    const u16* gB = B + (size_t)bcol * K_DIM;

    auto STAGE = [&](u16* lbuf, int k0) {
        u16* la = lbuf;
        u16* lb = lbuf + 8192;
#pragma unroll
        for (int j = 0; j < 4; ++j) {
            __builtin_amdgcn_global_load_lds(
                (const __attribute__((address_space(1))) uint32_t*)(gA + (size_t)rA[j] * K_DIM + k0 + cA[j]),
                (__attribute__((address_space(3))) uint32_t*)(la + wave * 512 + j * 2048), 16, 0, 0);
        }
#pragma unroll
        for (int j = 0; j < 2; ++j) {
            __builtin_amdgcn_global_load_lds(
                (const __attribute__((address_space(1))) uint32_t*)(gB + (size_t)rB[j] * K_DIM + k0 + cB[j]),
                (__attribute__((address_space(3))) uint32_t*)(lb + wave * 512 + j * 2048), 16, 0, 0);
        }
    };

    // per-lane swizzled read bases: key = ((lane&15)>>1)&3 (row>>1)&3 folds per-lane
    const uint32_t key  = (((uint32_t)lane & 15u) >> 1) & 3u;
    const uint32_t cpos = (((uint32_t)lane >> 4) << 4) ^ (key << 4);
    const uint32_t arow = ((uint32_t)wr * 128u + ((uint32_t)lane & 15u)) * 64u;
    const uint32_t brw  = ((uint32_t)wc * 64u  + ((uint32_t)lane & 15u)) * 64u;

    const char* pA0 = (const char*)&lds[0][0]    + arow + cpos;
    const char* pA1 = (const char*)&lds[1][0]    + arow + cpos;
    const char* pB0 = (const char*)&lds[0][8192] + brw  + cpos;
    const char* pB1 = (const char*)&lds[1][8192] + brw  + cpos;

    f32x4 acc[8][4];
#pragma unroll
    for (int m = 0; m < 8; ++m)
#pragma unroll
        for (int n = 0; n < 4; ++n) acc[m][n] = (f32x4){0.f, 0.f, 0.f, 0.f};

    short8 a[8], b[4];

    // ---- prologue: stage tiles 0 (buf0) and 1 (buf1) ----
    STAGE(&lds[0][0], 0);
    STAGE(&lds[1][0], 32);

    // ---- main loop: 64 iters x 2 bodies (tiles 2i in buf0, 2i+1 in buf1) ----
    for (int i = 0; i < K_DIM / 64; ++i) {
        const int k2a = (64 * i + 64) & (K_DIM - 1);   // tile 2i+2 (wraps last iter)
        const int k2b = (64 * i + 96) & (K_DIM - 1);   // tile 2i+3

        // body A: tile 2i from buf0
        WAIT_VM6();          // drain tile 2i (keeps 2i+1's 6)
        BAR();
        READ_A8(a, pA0);
        READ_B4(b, pB0);
        LGKM0();
        __builtin_amdgcn_s_setprio(1);
        MFMA32(a, b);
        __builtin_amdgcn_s_setprio(0);
        BAR();
        STAGE(&lds[0][0], k2a);

        // body B: tile 2i+1 from buf1
        WAIT_VM6();          // drain tile 2i+1 (keeps 2i+2's 6)
        BAR();
        READ_A8(a, pA1);
        READ_B4(b, pB1);
        LGKM0();
        __builtin_amdgcn_s_setprio(1);
        MFMA32(a, b);
        __builtin_amdgcn_s_setprio(0);
        BAR();
        STAGE(&lds[1][0], k2b);
    }

    WAIT_VM0();   // drain wrapped prefetches before epilogue

    // ---- epilogue: C/D layout col=lane&15, row=(lane>>4)*4+j ----
    const int orow = brow + wr * 128 + (lane >> 4) * 4;
    const int ocol = bcol + wc * 64 + (lane & 15);
#pragma unroll
    for (int n = 0; n < 4; ++n) {
        const int c = ocol + n * 16;
        const float bv = bias[c];
#pragma unroll
        for (int m = 0; m < 8; ++m) {
#pragma unroll
            for (int j = 0; j < 4; ++j) {
                C[(size_t)(orow + m * 16 + j) * N_DIM + c] = acc[m][n][j] + bv;
            }
        }
    }
}

// ---------- fallback (ws too small): correct, slow fp32 ----------
__global__ __launch_bounds__(256)
void gemm_f32_naive(const float* __restrict__ x, const float* __restrict__ w,
                    const float* __restrict__ bias, float* __restrict__ out) {
    const size_t total = (size_t)M_DIM * N_DIM;
    const size_t stride = (size_t)gridDim.x * blockDim.x;
    for (size_t idx = (size_t)blockIdx.x * blockDim.x + threadIdx.x; idx < total; idx += stride) {
        const int b = (int)(idx / N_DIM);
        const int o = (int)(idx % N_DIM);
        const float* xr = x + (size_t)b * K_DIM;
        const float* wr = w + (size_t)o * K_DIM;
        float s = bias[o];
        for (int k = 0; k < K_DIM; ++k) s = fmaf(xr[k], wr[k], s);
        out[idx] = s;
    }
}

extern "C" void kernel_launch(void* const* d_in, const int* in_sizes, int n_in,
                              void* d_out, int out_size, void* d_ws, size_t ws_size,
                              hipStream_t stream) {
    const float* x    = (const float*)d_in[0];
    const float* w    = (const float*)d_in[1];
    const float* bias = (const float*)d_in[2];
    float* out = (float*)d_out;

    const size_t xb_elems = (size_t)M_DIM * K_DIM;
    const size_t wb_elems = (size_t)N_DIM * K_DIM;
    const size_t need = (xb_elems + wb_elems) * sizeof(u16);

    if (ws_size >= need) {
        u16* xb = (u16*)d_ws;
        u16* wb = xb + xb_elems;
        cvt_f32_to_bf16_k<<<2048, 256, 0, stream>>>(x, xb, (int)(xb_elems / 8));
        cvt_f32_to_bf16_k<<<2048, 256, 0, stream>>>(w, wb, (int)(wb_elems / 8));
        const int nwg = (M_DIM / 256) * (N_DIM / 128);   // 32*32 = 1024
        gemm_tlp<<<nwg, 256, 0, stream>>>(xb, wb, bias, out);
    } else {
        gemm_f32_naive<<<4096, 256, 0, stream>>>(x, w, bias, out);
    }
}